// Round 7
// baseline (1272.262 us; speedup 1.0000x reference)
//
#include <hip/hip_runtime.h>

#define NN 100000
#define NE 1600000
#define TT 8
#define KF 160        // padded K: x 0..19 | pad 20..23 | agg 24..87 | h 88..151 | pad 152..159
#define XSTR 24       // xT row stride (20 + 4 zero pad), bf16
#define HISTB 6250    // hist blocks in the merged hist+xt kernel
#define NRANGE 8      // scatter dst ranges (XCD-pinned via blockIdx&7)
#define RSPAN 12500   // NN / NRANGE

typedef __attribute__((ext_vector_type(8))) short bf16x8;
typedef __attribute__((ext_vector_type(4))) float f32x4;
typedef unsigned int uint_;
typedef unsigned short ushort_;

__device__ __forceinline__ float sigf(float x) { return 1.f / (1.f + __expf(-x)); }
__device__ __forceinline__ float tanhf_(float x) { return 1.f - 2.f / (__expf(2.f * x) + 1.f); }
__device__ __forceinline__ ushort_ f2b(float f) {
    uint_ u = __float_as_uint(f);
    u += 0x7fff + ((u >> 16) & 1);
    return (ushort_)(u >> 16);
}
__device__ __forceinline__ float bl(uint_ u) { return __uint_as_float(u << 16); }
__device__ __forceinline__ float bh(uint_ u) { return __uint_as_float(u & 0xffff0000u); }
__device__ __forceinline__ void acc8(float* a, uint4 v) {
    a[0] += bl(v.x); a[1] += bh(v.x); a[2] += bl(v.y); a[3] += bh(v.y);
    a[4] += bl(v.z); a[5] += bh(v.z); a[6] += bl(v.w); a[7] += bh(v.w);
}
__device__ __forceinline__ uint_ pk(float a, float b) {
    return (uint_)f2b(a) | ((uint_)f2b(b) << 16);
}

// ---------------- edge dtype detect: int64 => odd int32 words are all 0 ----------------
__global__ void k_detect(const int* __restrict__ ei, int* flag) {
    int i = blockIdx.x * 256 + threadIdx.x;
    if (ei[2 * i + 1] != 0) atomicOr(flag, 1);
}

// ---------------- merged: dst histogram + x transpose (independent work, overlapped) ----------------
__global__ void k_hist_xt(const int* __restrict__ ei, const int* __restrict__ flag, int* cnt,
                          const float* __restrict__ x, ushort_* __restrict__ xT) {
    int b = blockIdx.x;
    if (b < HISTB) {
        int e = b * 256 + threadIdx.x;
        if (e >= NE) return;
        int is32 = *flag;
        int d = is32 ? ei[NE + e] : ei[2 * (NE + e)];
        atomicAdd(&cnt[d], 1);
    } else {
        if (!xT) return;
        int i = (b - HISTB) * 256 + threadIdx.x;   // n*24 + kk
        if (i >= NN * XSTR) return;
        int n = i / XSTR, kk = i - n * XSTR;
        if (kk < 20) {
            const float* xp = x + (size_t)n * 240 + (10 + kk) * 8;
#pragma unroll
            for (int t = 0; t < 8; t++) xT[(size_t)t * NN * XSTR + i] = f2b(xp[t]);
        } else {
#pragma unroll
            for (int t = 0; t < 8; t++) xT[(size_t)t * NN * XSTR + i] = 0;
        }
    }
}

// ---------------- CSR scan ----------------
__global__ void k_scanblk(const int* __restrict__ cnt, int* off, int* bsum) {
    __shared__ int tmp[1024];
    int i = blockIdx.x * 1024 + threadIdx.x;
    int v = (i < NN) ? cnt[i] : 0;
    tmp[threadIdx.x] = v;
    __syncthreads();
    for (int d = 1; d < 1024; d <<= 1) {
        int t = (threadIdx.x >= d) ? tmp[threadIdx.x - d] : 0;
        __syncthreads();
        tmp[threadIdx.x] += t;
        __syncthreads();
    }
    if (i < NN) off[i + 1] = tmp[threadIdx.x];
    if (threadIdx.x == 1023) bsum[blockIdx.x] = tmp[1023];
}

__global__ void k_scantop(int* bsum, int nb) {
    if (threadIdx.x == 0) {
        int run = 0;
        for (int b = 0; b < nb; b++) { int t = bsum[b]; bsum[b] = run; run += t; }
    }
}

__global__ void k_scanadd(int* off, const int* __restrict__ bsum) {
    int i = blockIdx.x * 1024 + threadIdx.x;
    if (i < NN) off[i + 1] += bsum[blockIdx.x];
    if (i == 0) off[0] = 0;
}

// ---------------- scatter, dst-range partitioned (range pinned to XCD via blockIdx&7) ----------------
__global__ void k_scatter(const int* __restrict__ ei, const int* __restrict__ flag,
                          int* cursor, int* csr) {
    int b = blockIdx.x;
    int range = b & (NRANGE - 1), chunk = b >> 3;
    int e = chunk * 256 + threadIdx.x;
    if (e >= NE) return;
    int is32 = *flag;
    int d = is32 ? ei[NE + e] : ei[2 * (NE + e)];
    if (d / RSPAN != range) return;
    int s = is32 ? ei[e] : ei[2 * e];
    int pos = atomicAdd(&cursor[d], 1);
    csr[pos] = s;
}

// ---------------- fold weights into WgB bf16 [n=320][KF], gate-interleaved cols ----------------
__global__ void k_prep(const float* __restrict__ W_ih, const float* __restrict__ W_hh,
                       const float* __restrict__ b_ih, const float* __restrict__ b_hh,
                       const float* __restrict__ W_rel, const float* __restrict__ b_rel,
                       const float* __restrict__ W_root, ushort_* WgB, float* bgp) {
    int n = threadIdx.x;          // 0..319
    int k = blockIdx.x;           // 0..159 rows; 160 => bias
    if (k < KF) {
        float v = 0.f;
        if (n < 256) {
            int w = n >> 6, g = (n >> 4) & 3, j = w * 16 + (n & 15);
            int row = g * 64 + j;
            if (k < 20) {
                v = W_ih[row * 84 + k];
            } else if (k >= 24 && k < 88) {
                int kk = k - 24;
                float a = 0.f;
                for (int m = 0; m < 64; m++) a += W_ih[row * 84 + 20 + m] * W_rel[m * 64 + kk];
                v = a;
            } else if (k >= 88 && k < 152) {
                int kk = k - 88;
                float a = W_hh[row * 64 + kk];
                for (int m = 0; m < 64; m++) a += W_ih[row * 84 + 20 + m] * W_root[m * 64 + kk];
                v = a;
            }
        } else {
            int j = n - 256;
            if (k >= 24 && k < 88) v = W_rel[j * 64 + (k - 24)];
            else if (k >= 88 && k < 152) v = W_root[j * 64 + (k - 88)];
        }
        WgB[(size_t)n * KF + k] = f2b(v);
    } else {
        if (n < 256) {
            int j = n >> 2, g = n & 3;            // bgp[j*4+g]
            int row = g * 64 + j;
            float a = b_ih[row] + b_hh[row];
            for (int m = 0; m < 64; m++) a += W_ih[row * 84 + 20 + m] * b_rel[m];
            bgp[n] = a;
        } else {
            bgp[n] = b_rel[n - 256];
        }
    }
}

// ---------------- fused step body: gather + MFMA gates + LSTM cell, full-line epilogue ----------------
template <bool LAST>
__device__ __forceinline__ void step_body(const float* __restrict__ x,
                                          const ushort_* __restrict__ xT,
                                          const int* __restrict__ off,
                                          const int* __restrict__ csr,
                                          const ushort_* __restrict__ hbR,
                                          ushort_* __restrict__ hbW,
                                          float* __restrict__ hf,
                                          float* __restrict__ c,
                                          const ushort_* __restrict__ WgB,
                                          const float* __restrict__ bgp,
                                          float* __restrict__ gnn,
                                          float* __restrict__ sums,
                                          float* __restrict__ sumsq, int t) {
    constexpr int NT = LAST ? 5 : 4;
    __shared__ __align__(16) ushort_ Zs[64 * 168];   // [node][KF pad 168]; reused by epilogue
    const int tid = threadIdx.x;
    const int nblk = blockIdx.x * 64;
    const int w = tid >> 6, lane = tid & 63;
    const int q = lane >> 4, l16 = lane & 15;

    // ---- stage x (octs 0..2), h (octs 11..18), zero-pad (oct 19): 64 nodes x 12 slots ----
#pragma unroll
    for (int i = 0; i < 3; ++i) {
        int slot = tid + 256 * i;
        int n = slot / 12, oo = slot - n * 12;
        int n_g = nblk + n;
        uint4 z = make_uint4(0, 0, 0, 0);
        if (n_g < NN) {
            if (oo < 3) {
                if (xT) {
                    z = *(const uint4*)(xT + ((size_t)t * NN + n_g) * XSTR + oo * 8);
                } else {
                    const float* xp = x + (size_t)n_g * 240 + 80 + (size_t)oo * 64 + t;
                    uint_ r[4];
#pragma unroll
                    for (int p = 0; p < 4; p++) {
                        int k0 = oo * 8 + p * 2;
                        ushort_ b0 = (k0 < 20) ? f2b(xp[p * 16]) : (ushort_)0;
                        ushort_ b1 = (k0 + 1 < 20) ? f2b(xp[p * 16 + 8]) : (ushort_)0;
                        r[p] = (uint_)b0 | ((uint_)b1 << 16);
                    }
                    z = make_uint4(r[0], r[1], r[2], r[3]);
                }
            } else if (oo < 11) {
                z = *(const uint4*)(hbR + (size_t)n_g * 64 + (oo - 3) * 8);
            }
        }
        int oct = (oo < 3) ? oo : ((oo < 11) ? (oo + 8) : 19);
        *(uint4*)(Zs + n * 168 + oct * 8) = z;
    }

    // ---- gather phase: 8-lane group per node, lane l8 owns features l8*8..+7, fp32 accum ----
    {
        int slot = tid >> 3;       // 0..31
        int l8 = tid & 7;
        for (int nn = slot; nn < 64; nn += 32) {
            int node = nblk + nn;
            float a[8];
#pragma unroll
            for (int i = 0; i < 8; i++) a[i] = 0.f;
            if (t > 0 && node < NN) {
                int e0 = off[node], e1 = off[node + 1];
                int e = e0;
                for (; e + 8 <= e1; e += 8) {
                    uint4 v0 = *(const uint4*)(hbR + (size_t)csr[e] * 64 + l8 * 8);
                    uint4 v1 = *(const uint4*)(hbR + (size_t)csr[e + 1] * 64 + l8 * 8);
                    uint4 v2 = *(const uint4*)(hbR + (size_t)csr[e + 2] * 64 + l8 * 8);
                    uint4 v3 = *(const uint4*)(hbR + (size_t)csr[e + 3] * 64 + l8 * 8);
                    uint4 v4 = *(const uint4*)(hbR + (size_t)csr[e + 4] * 64 + l8 * 8);
                    uint4 v5 = *(const uint4*)(hbR + (size_t)csr[e + 5] * 64 + l8 * 8);
                    uint4 v6 = *(const uint4*)(hbR + (size_t)csr[e + 6] * 64 + l8 * 8);
                    uint4 v7 = *(const uint4*)(hbR + (size_t)csr[e + 7] * 64 + l8 * 8);
                    acc8(a, v0); acc8(a, v1); acc8(a, v2); acc8(a, v3);
                    acc8(a, v4); acc8(a, v5); acc8(a, v6); acc8(a, v7);
                }
                for (; e < e1; e++) {
                    uint4 v0 = *(const uint4*)(hbR + (size_t)csr[e] * 64 + l8 * 8);
                    acc8(a, v0);
                }
            }
            uint4 o;
            o.x = pk(a[0], a[1]); o.y = pk(a[2], a[3]);
            o.z = pk(a[4], a[5]); o.w = pk(a[6], a[7]);
            *(uint4*)(Zs + nn * 168 + 24 + l8 * 8) = o;   // kk 24..87
        }
    }
    __syncthreads();   // Zs complete

    f32x4 acc[4][NT];
#pragma unroll
    for (int mt = 0; mt < 4; mt++)
#pragma unroll
        for (int nt = 0; nt < NT; nt++) acc[mt][nt] = (f32x4)(0.f);

#pragma unroll
    for (int kt = 0; kt < 5; ++kt) {
        bf16x8 af[4], bf[NT];
#pragma unroll
        for (int mt = 0; mt < 4; mt++)
            af[mt] = *(const bf16x8*)(Zs + (mt * 16 + l16) * 168 + kt * 32 + q * 8);
#pragma unroll
        for (int nt = 0; nt < NT; nt++) {
            int n = (nt < 4) ? (w * 64 + nt * 16 + l16) : (256 + w * 16 + l16);
            bf[nt] = *(const bf16x8*)(WgB + (size_t)n * KF + kt * 32 + q * 8);
        }
#pragma unroll
        for (int mt = 0; mt < 4; mt++)
#pragma unroll
            for (int nt = 0; nt < NT; nt++)
                acc[mt][nt] = __builtin_amdgcn_mfma_f32_16x16x32_bf16(af[mt], bf[nt], acc[mt][nt], 0, 0, 0);
    }

    // ---- epilogue: compute cell update; stage in LDS; full-line cooperative stores ----
    const int j = w * 16 + l16;
    const f32x4 bias = *(const f32x4*)(bgp + j * 4);
    const float brl = LAST ? bgp[256 + j] : 0.f;
    float sh = 0.f, sh2 = 0.f, sg = 0.f, sg2 = 0.f;

    __syncthreads();   // all Zs fragment reads done — Zs reusable
    ushort_* Hs   = Zs;                      // [64][64] bf16, bytes [0, 8192)
    float*   CsLo = (float*)(Zs + 4096);     // [32][64] fp32, bytes [8192, 16384)

    float cnHi[8];
#pragma unroll
    for (int mt = 0; mt < 4; ++mt) {
#pragma unroll
        for (int r = 0; r < 4; ++r) {
            int nloc = mt * 16 + q * 4 + r;
            int node = nblk + nloc;
            float cn = 0.f, hn = 0.f;
            if (node < NN) {
                size_t idx = (size_t)node * 64 + j;
                float iv = sigf(acc[mt][0][r] + bias.x);
                float fv = sigf(acc[mt][1][r] + bias.y);
                float gv = tanhf_(acc[mt][2][r] + bias.z);
                float ov = sigf(acc[mt][3][r] + bias.w);
                cn = fv * c[idx] + iv * gv;
                hn = ov * tanhf_(cn);
                if (LAST) {
                    float gn = acc[mt][4][r] + brl;
                    hf[idx] = hn;
                    gnn[idx] = gn;
                    sh += hn; sh2 += hn * hn;
                    sg += gn; sg2 += gn * gn;
                }
            }
            Hs[nloc * 64 + j] = f2b(hn);
            if (mt < 2) CsLo[nloc * 64 + j] = cn;
            else        cnHi[(mt - 2) * 4 + r] = cn;
        }
    }
    __syncthreads();
    // hbW: 64 rows x 128 B; c low: 32 rows x 256 B — both fully coalesced 16 B/lane
#pragma unroll
    for (int i = 0; i < 2; ++i) {
        int s = tid + 256 * i;
        {
            int n = s >> 3, part = s & 7;
            if (nblk + n < NN)
                *(uint4*)(hbW + (size_t)(nblk + n) * 64 + part * 8) =
                    *(const uint4*)(Hs + n * 64 + part * 8);
        }
        {
            int n = s >> 4, part = s & 15;
            if (nblk + n < NN)
                *(float4*)(c + (size_t)(nblk + n) * 64 + part * 4) =
                    *(const float4*)(CsLo + n * 64 + part * 4);
        }
    }
    __syncthreads();
    float* CsHi = (float*)Zs;   // [32][64] for nodes 32..63
#pragma unroll
    for (int mt = 2; mt < 4; ++mt)
#pragma unroll
        for (int r = 0; r < 4; ++r) {
            int nloc = mt * 16 + q * 4 + r;
            CsHi[(nloc - 32) * 64 + j] = cnHi[(mt - 2) * 4 + r];
        }
    __syncthreads();
#pragma unroll
    for (int i = 0; i < 2; ++i) {
        int s = tid + 256 * i;
        int n = 32 + (s >> 4), part = s & 15;
        if (nblk + n < NN)
            *(float4*)(c + (size_t)(nblk + n) * 64 + part * 4) =
                *(const float4*)(CsHi + (n - 32) * 64 + part * 4);
    }

    if (LAST) {
#pragma unroll
        for (int d = 16; d < 64; d <<= 1) {
            sh += __shfl_xor(sh, d, 64);
            sh2 += __shfl_xor(sh2, d, 64);
            sg += __shfl_xor(sg, d, 64);
            sg2 += __shfl_xor(sg2, d, 64);
        }
        if (q == 0) {
            atomicAdd(&sums[j], sh);
            atomicAdd(&sumsq[j], sh2);
            atomicAdd(&sums[64 + j], sg);
            atomicAdd(&sumsq[64 + j], sg2);
        }
    }
}

__global__ __launch_bounds__(256, 6) void k_step(const float* __restrict__ x,
                                                 const ushort_* __restrict__ xT,
                                                 const int* __restrict__ off,
                                                 const int* __restrict__ csr,
                                                 const ushort_* __restrict__ hbR,
                                                 ushort_* __restrict__ hbW,
                                                 float* __restrict__ hf,
                                                 float* __restrict__ c,
                                                 const ushort_* __restrict__ WgB,
                                                 const float* __restrict__ bgp, int t) {
    step_body<false>(x, xT, off, csr, hbR, hbW, hf, c, WgB, bgp, nullptr, nullptr, nullptr, t);
}

__global__ __launch_bounds__(256, 4) void k_stepL(const float* __restrict__ x,
                                                  const ushort_* __restrict__ xT,
                                                  const int* __restrict__ off,
                                                  const int* __restrict__ csr,
                                                  const ushort_* __restrict__ hbR,
                                                  ushort_* __restrict__ hbW,
                                                  float* __restrict__ hf,
                                                  float* __restrict__ c,
                                                  const ushort_* __restrict__ WgB,
                                                  const float* __restrict__ bgp,
                                                  float* __restrict__ gnn,
                                                  float* __restrict__ sums,
                                                  float* __restrict__ sumsq, int t) {
    step_body<true>(x, xT, off, csr, hbR, hbW, hf, c, WgB, bgp, gnn, sums, sumsq, t);
}

// ---------------- MFMA head: BN-apply + relu(W1) + relu(W2) + sigmoid(W_out) ----------------
__global__ __launch_bounds__(256) void k_head(const float* __restrict__ hf,
                                              const float* __restrict__ gnn,
                                              const float* __restrict__ sums,
                                              const float* __restrict__ sumsq,
                                              const float* __restrict__ gamma,
                                              const float* __restrict__ beta,
                                              const float* __restrict__ W1,
                                              const float* __restrict__ b1,
                                              const float* __restrict__ W2,
                                              const float* __restrict__ b2,
                                              const float* __restrict__ W_out,
                                              const float* __restrict__ b_out,
                                              float* __restrict__ out) {
    __shared__ __align__(16) ushort_ Zs[64 * 168];    // normed [node][F pad]
    __shared__ __align__(16) ushort_ W1s[64 * 168];   // W1 rows [j][k=128 pad]
    __shared__ __align__(16) ushort_ W2s[128 * 72];   // W2 rows [j2][k=64 pad]
    __shared__ __align__(16) ushort_ H1s[64 * 72];    // h1 bf16 [node][j pad]
    __shared__ float ab[256];
    __shared__ float Obuf[4][64];
    const int tid = threadIdx.x;
    const int w = tid >> 6, lane = tid & 63;
    const int q = lane >> 4, l16 = lane & 15;

    if (tid < 128) {
        float mean = sums[tid] / (float)NN;
        float var = sumsq[tid] / (float)NN - mean * mean;
        float a = gamma[tid] * rsqrtf(var + 1e-5f);
        ab[tid] = a;
        ab[128 + tid] = beta[tid] - mean * a;
    }
#pragma unroll
    for (int i = 0; i < 8; ++i) {
        int slot = tid + 256 * i;
        int jj = slot >> 5, k4 = slot & 31;
        float4 v = *(const float4*)(W1 + (size_t)jj * 128 + k4 * 4);
        *(uint2*)(W1s + jj * 168 + k4 * 4) = make_uint2(pk(v.x, v.y), pk(v.z, v.w));
    }
#pragma unroll
    for (int i = 0; i < 8; ++i) {
        int slot = tid + 256 * i;
        int jj = slot >> 4, k4 = slot & 15;
        float4 v = *(const float4*)(W2 + (size_t)jj * 64 + k4 * 4);
        *(uint2*)(W2s + jj * 72 + k4 * 4) = make_uint2(pk(v.x, v.y), pk(v.z, v.w));
    }
    const int j1 = w * 16 + l16;
    const float bb1 = b1[j1];
    const int j2a = (w * 2) * 16 + l16, j2b = (w * 2 + 1) * 16 + l16;
    const float bb2a = b2[j2a], bb2b = b2[j2b];
    const float woa = W_out[j2a], wob = W_out[j2b];
    const float bo = b_out[0];
    __syncthreads();

    const int NTILE = (NN + 63) / 64;
    for (int tile = blockIdx.x; tile < NTILE; tile += gridDim.x) {
        const int nblk = tile * 64;
#pragma unroll
        for (int i = 0; i < 8; ++i) {
            int slot = tid + 256 * i;
            int n = slot >> 5, f4 = slot & 31;
            int n_g = nblk + n;
            uint2 z = make_uint2(0, 0);
            if (n_g < NN) {
                const float* src = (f4 < 16) ? (hf + (size_t)n_g * 64 + f4 * 4)
                                             : (gnn + (size_t)n_g * 64 + (f4 - 16) * 4);
                float4 v = *(const float4*)src;
                int F = f4 * 4;
                z = make_uint2(pk(v.x * ab[F] + ab[128 + F], v.y * ab[F + 1] + ab[129 + F]),
                               pk(v.z * ab[F + 2] + ab[130 + F], v.w * ab[F + 3] + ab[131 + F]));
            }
            *(uint2*)(Zs + n * 168 + f4 * 4) = z;
        }
        __syncthreads();
        f32x4 acc1[4];
#pragma unroll
        for (int mt = 0; mt < 4; mt++) acc1[mt] = (f32x4)(0.f);
#pragma unroll
        for (int kt = 0; kt < 4; ++kt) {
            bf16x8 bfw = *(const bf16x8*)(W1s + j1 * 168 + kt * 32 + q * 8);
#pragma unroll
            for (int mt = 0; mt < 4; mt++) {
                bf16x8 af = *(const bf16x8*)(Zs + (mt * 16 + l16) * 168 + kt * 32 + q * 8);
                acc1[mt] = __builtin_amdgcn_mfma_f32_16x16x32_bf16(af, bfw, acc1[mt], 0, 0, 0);
            }
        }
#pragma unroll
        for (int mt = 0; mt < 4; mt++)
#pragma unroll
            for (int r = 0; r < 4; r++) {
                int nloc = mt * 16 + q * 4 + r;
                H1s[nloc * 72 + j1] = f2b(fmaxf(acc1[mt][r] + bb1, 0.f));
            }
        __syncthreads();
        f32x4 acc2[4][2];
#pragma unroll
        for (int mt = 0; mt < 4; mt++)
#pragma unroll
            for (int nt = 0; nt < 2; nt++) acc2[mt][nt] = (f32x4)(0.f);
#pragma unroll
        for (int kt = 0; kt < 2; ++kt) {
            bf16x8 bfa = *(const bf16x8*)(W2s + j2a * 72 + kt * 32 + q * 8);
            bf16x8 bfb = *(const bf16x8*)(W2s + j2b * 72 + kt * 32 + q * 8);
#pragma unroll
            for (int mt = 0; mt < 4; mt++) {
                bf16x8 af = *(const bf16x8*)(H1s + (mt * 16 + l16) * 72 + kt * 32 + q * 8);
                acc2[mt][0] = __builtin_amdgcn_mfma_f32_16x16x32_bf16(af, bfa, acc2[mt][0], 0, 0, 0);
                acc2[mt][1] = __builtin_amdgcn_mfma_f32_16x16x32_bf16(af, bfb, acc2[mt][1], 0, 0, 0);
            }
        }
#pragma unroll
        for (int mt = 0; mt < 4; mt++) {
#pragma unroll
            for (int r = 0; r < 4; r++) {
                float p = fmaxf(acc2[mt][0][r] + bb2a, 0.f) * woa +
                          fmaxf(acc2[mt][1][r] + bb2b, 0.f) * wob;
#pragma unroll
                for (int d = 1; d < 16; d <<= 1) p += __shfl_xor(p, d, 64);
                if (l16 == 0) Obuf[w][mt * 16 + q * 4 + r] = p;
            }
        }
        __syncthreads();
        if (tid < 64) {
            int n_g = nblk + tid;
            if (n_g < NN) {
                float s = Obuf[0][tid] + Obuf[1][tid] + Obuf[2][tid] + Obuf[3][tid];
                out[n_g] = sigf(s + bo);
            }
        }
        __syncthreads();
    }
}

extern "C" void kernel_launch(void* const* d_in, const int* in_sizes, int n_in,
                              void* d_out, int out_size, void* d_ws, size_t ws_size,
                              hipStream_t stream) {
    const float* x      = (const float*)d_in[0];
    const int*   ei     = (const int*)d_in[1];
    const float* W_ih   = (const float*)d_in[4];
    const float* W_hh   = (const float*)d_in[5];
    const float* b_ih   = (const float*)d_in[6];
    const float* b_hh   = (const float*)d_in[7];
    const float* W_rel  = (const float*)d_in[8];
    const float* b_rel  = (const float*)d_in[9];
    const float* W_root = (const float*)d_in[10];
    const float* gamma  = (const float*)d_in[11];
    const float* beta   = (const float*)d_in[12];
    const float* W1     = (const float*)d_in[13];
    const float* b1     = (const float*)d_in[14];
    const float* W2     = (const float*)d_in[15];
    const float* b2     = (const float*)d_in[16];
    const float* W_out  = (const float*)d_in[17];
    const float* b_out  = (const float*)d_in[18];
    float* out = (float*)d_out;

    char* ws = (char*)d_ws;
    size_t o = 0;
    auto carve = [&](size_t bytes) { char* p = ws + o; o += (bytes + 255) & ~(size_t)255; return p; };
    int*     off   = (int*)carve((NN + 1) * 4);
    int*     cnt   = (int*)carve(NN * 4);          // reused as cursor
    int*     bsum  = (int*)carve(128 * 4);
    int*     flag  = (int*)carve(256);
    int*     csr   = (int*)carve((size_t)NE * 4);
    float*   hf    = (float*)carve((size_t)NN * 64 * 4);   // fp32 h (written at t=7 only)
    float*   c     = (float*)carve((size_t)NN * 64 * 4);
    float*   gnn   = (float*)carve((size_t)NN * 64 * 4);
    ushort_* hbA   = (ushort_*)carve((size_t)NN * 64 * 2); // bf16 h ping
    ushort_* hbB   = (ushort_*)carve((size_t)NN * 64 * 2); // bf16 h pong
    ushort_* WgB   = (ushort_*)carve((size_t)320 * KF * 2);
    float*   bgp   = (float*)carve(320 * 4);
    float*   sums  = (float*)carve(128 * 4);
    float*   sumsq = (float*)carve(128 * 4);
    ushort_* xT = nullptr;
    size_t need_xt = (size_t)TT * NN * XSTR * 2;
    if (o + need_xt + 256 <= ws_size) xT = (ushort_*)carve(need_xt);

    const int nscan = (NN + 1023) / 1024;   // 98
    const int xtb = xT ? (NN * XSTR + 255) / 256 : 0;

    // edge dtype detect + CSR build (+ x transpose overlapped with hist)
    hipMemsetAsync(flag, 0, 4, stream);
    hipMemsetAsync(cnt, 0, NN * 4, stream);
    k_detect<<<16, 256, 0, stream>>>(ei, flag);
    k_hist_xt<<<HISTB + xtb, 256, 0, stream>>>(ei, flag, cnt, x, xT);
    k_scanblk<<<nscan, 1024, 0, stream>>>(cnt, off, bsum);
    k_scantop<<<1, 64, 0, stream>>>(bsum, nscan);
    k_scanadd<<<nscan, 1024, 0, stream>>>(off, bsum);
    hipMemcpyAsync(cnt, off, NN * 4, hipMemcpyDeviceToDevice, stream);  // cursor = off
    k_scatter<<<(NE / 256) * NRANGE, 256, 0, stream>>>(ei, flag, cnt, csr);

    // init state + folded weights + BN accumulators
    hipMemsetAsync(c, 0, (size_t)NN * 64 * 4, stream);
    hipMemsetAsync(hbA, 0, (size_t)NN * 64 * 2, stream);   // t=0 reads hbA
    hipMemsetAsync(sums, 0, 1024, stream);                 // sums + sumsq (contiguous carves)
    k_prep<<<KF + 1, 320, 0, stream>>>(W_ih, W_hh, b_ih, b_hh, W_rel, b_rel, W_root, WgB, bgp);

    // 8 fused steps (ping-pong bf16 h)
    const int ngates = (NN + 63) / 64;
    for (int t = 0; t < TT; ++t) {
        ushort_* hbR = (t & 1) ? hbB : hbA;
        ushort_* hbW = (t & 1) ? hbA : hbB;
        if (t == TT - 1)
            k_stepL<<<ngates, 256, 0, stream>>>(x, xT, off, csr, hbR, hbW, hf, c,
                                                WgB, bgp, gnn, sums, sumsq, t);
        else
            k_step<<<ngates, 256, 0, stream>>>(x, xT, off, csr, hbR, hbW, hf, c,
                                               WgB, bgp, t);
    }

    // fused MFMA head
    k_head<<<512, 256, 0, stream>>>(hf, gnn, sums, sumsq, gamma, beta,
                                    W1, b1, W2, b2, W_out, b_out, out);
}

// Round 8
// 918.693 us; speedup vs baseline: 1.3849x; 1.3849x over previous
//
#include <hip/hip_runtime.h>

#define NN 100000
#define NE 1600000
#define TT 8
#define KF 160        // padded K: x 0..19 | pad 20..23 | agg 24..87 | h 88..151 | pad 152..159
#define XSTR 24       // xT row stride (20 + 4 zero pad), bf16
#define HISTB 6250    // hist blocks in the merged hist+xt kernel
#define NRANGE 8      // scatter dst ranges (XCD-pinned via blockIdx&7)
#define RSPAN 12500   // NN / NRANGE

typedef __attribute__((ext_vector_type(8))) short bf16x8;
typedef __attribute__((ext_vector_type(4))) float f32x4;
typedef unsigned int uint_;
typedef unsigned short ushort_;

__device__ __forceinline__ float sigf(float x) { return 1.f / (1.f + __expf(-x)); }
__device__ __forceinline__ float tanhf_(float x) { return 1.f - 2.f / (__expf(2.f * x) + 1.f); }
__device__ __forceinline__ ushort_ f2b(float f) {
    uint_ u = __float_as_uint(f);
    u += 0x7fff + ((u >> 16) & 1);
    return (ushort_)(u >> 16);
}
__device__ __forceinline__ float bl(uint_ u) { return __uint_as_float(u << 16); }
__device__ __forceinline__ float bh(uint_ u) { return __uint_as_float(u & 0xffff0000u); }
__device__ __forceinline__ void acc8(float* a, uint4 v) {
    a[0] += bl(v.x); a[1] += bh(v.x); a[2] += bl(v.y); a[3] += bh(v.y);
    a[4] += bl(v.z); a[5] += bh(v.z); a[6] += bl(v.w); a[7] += bh(v.w);
}
__device__ __forceinline__ uint_ pk(float a, float b) {
    return (uint_)f2b(a) | ((uint_)f2b(b) << 16);
}

// ---------------- edge dtype detect: int64 => odd int32 words are all 0 ----------------
__global__ void k_detect(const int* __restrict__ ei, int* flag) {
    int i = blockIdx.x * 256 + threadIdx.x;
    if (ei[2 * i + 1] != 0) atomicOr(flag, 1);
}

// ---------------- merged: dst histogram + x transpose (independent work, overlapped) ----------------
__global__ void k_hist_xt(const int* __restrict__ ei, const int* __restrict__ flag, int* cnt,
                          const float* __restrict__ x, ushort_* __restrict__ xT) {
    int b = blockIdx.x;
    if (b < HISTB) {
        int e = b * 256 + threadIdx.x;
        if (e >= NE) return;
        int is32 = *flag;
        int d = is32 ? ei[NE + e] : ei[2 * (NE + e)];
        atomicAdd(&cnt[d], 1);
    } else {
        if (!xT) return;
        int i = (b - HISTB) * 256 + threadIdx.x;   // n*24 + kk
        if (i >= NN * XSTR) return;
        int n = i / XSTR, kk = i - n * XSTR;
        if (kk < 20) {
            const float* xp = x + (size_t)n * 240 + (10 + kk) * 8;
#pragma unroll
            for (int t = 0; t < 8; t++) xT[(size_t)t * NN * XSTR + i] = f2b(xp[t]);
        } else {
#pragma unroll
            for (int t = 0; t < 8; t++) xT[(size_t)t * NN * XSTR + i] = 0;
        }
    }
}

// ---------------- CSR scan ----------------
__global__ void k_scanblk(const int* __restrict__ cnt, int* off, int* bsum) {
    __shared__ int tmp[1024];
    int i = blockIdx.x * 1024 + threadIdx.x;
    int v = (i < NN) ? cnt[i] : 0;
    tmp[threadIdx.x] = v;
    __syncthreads();
    for (int d = 1; d < 1024; d <<= 1) {
        int t = (threadIdx.x >= d) ? tmp[threadIdx.x - d] : 0;
        __syncthreads();
        tmp[threadIdx.x] += t;
        __syncthreads();
    }
    if (i < NN) off[i + 1] = tmp[threadIdx.x];
    if (threadIdx.x == 1023) bsum[blockIdx.x] = tmp[1023];
}

__global__ void k_scantop(int* bsum, int nb) {
    if (threadIdx.x == 0) {
        int run = 0;
        for (int b = 0; b < nb; b++) { int t = bsum[b]; bsum[b] = run; run += t; }
    }
}

__global__ void k_scanadd(int* off, const int* __restrict__ bsum) {
    int i = blockIdx.x * 1024 + threadIdx.x;
    if (i < NN) off[i + 1] += bsum[blockIdx.x];
    if (i == 0) off[0] = 0;
}

// ---------------- scatter, dst-range partitioned (range pinned to XCD via blockIdx&7) ----------------
__global__ void k_scatter(const int* __restrict__ ei, const int* __restrict__ flag,
                          int* cursor, int* csr) {
    int b = blockIdx.x;
    int range = b & (NRANGE - 1), chunk = b >> 3;
    int e = chunk * 256 + threadIdx.x;
    if (e >= NE) return;
    int is32 = *flag;
    int d = is32 ? ei[NE + e] : ei[2 * (NE + e)];
    if (d / RSPAN != range) return;
    int s = is32 ? ei[e] : ei[2 * e];
    int pos = atomicAdd(&cursor[d], 1);
    csr[pos] = s;
}

// ---------------- fold weights into WgB bf16 [n=320][KF], gate-interleaved cols ----------------
__global__ void k_prep(const float* __restrict__ W_ih, const float* __restrict__ W_hh,
                       const float* __restrict__ b_ih, const float* __restrict__ b_hh,
                       const float* __restrict__ W_rel, const float* __restrict__ b_rel,
                       const float* __restrict__ W_root, ushort_* WgB, float* bgp) {
    int n = threadIdx.x;          // 0..319
    int k = blockIdx.x;           // 0..159 rows; 160 => bias
    if (k < KF) {
        float v = 0.f;
        if (n < 256) {
            int w = n >> 6, g = (n >> 4) & 3, j = w * 16 + (n & 15);
            int row = g * 64 + j;
            if (k < 20) {
                v = W_ih[row * 84 + k];
            } else if (k >= 24 && k < 88) {
                int kk = k - 24;
                float a = 0.f;
                for (int m = 0; m < 64; m++) a += W_ih[row * 84 + 20 + m] * W_rel[m * 64 + kk];
                v = a;
            } else if (k >= 88 && k < 152) {
                int kk = k - 88;
                float a = W_hh[row * 64 + kk];
                for (int m = 0; m < 64; m++) a += W_ih[row * 84 + 20 + m] * W_root[m * 64 + kk];
                v = a;
            }
        } else {
            int j = n - 256;
            if (k >= 24 && k < 88) v = W_rel[j * 64 + (k - 24)];
            else if (k >= 88 && k < 152) v = W_root[j * 64 + (k - 88)];
        }
        WgB[(size_t)n * KF + k] = f2b(v);
    } else {
        if (n < 256) {
            int j = n >> 2, g = n & 3;            // bgp[j*4+g]
            int row = g * 64 + j;
            float a = b_ih[row] + b_hh[row];
            for (int m = 0; m < 64; m++) a += W_ih[row * 84 + 20 + m] * b_rel[m];
            bgp[n] = a;
        } else {
            bgp[n] = b_rel[n - 256];
        }
    }
}

// ---------------- fused step body: gather + MFMA gates + LSTM cell, full-line epilogue ----------------
// NOTE: __launch_bounds__ must stay at (256,4): 128 regs/thread = 64 AGPR acc + 64 VGPR.
// (256,6) caps at ~85/thread and spills — R7 showed +117 MB scratch writes, +20 µs/step.
template <bool LAST>
__device__ __forceinline__ void step_body(const float* __restrict__ x,
                                          const ushort_* __restrict__ xT,
                                          const int* __restrict__ off,
                                          const int* __restrict__ csr,
                                          const ushort_* __restrict__ hbR,
                                          ushort_* __restrict__ hbW,
                                          float* __restrict__ hf,
                                          float* __restrict__ c,
                                          const ushort_* __restrict__ WgB,
                                          const float* __restrict__ bgp,
                                          float* __restrict__ gnn,
                                          float* __restrict__ sums,
                                          float* __restrict__ sumsq, int t) {
    constexpr int NT = LAST ? 5 : 4;
    __shared__ __align__(16) ushort_ Zs[64 * 168];   // [node][KF pad 168]; reused by epilogue
    const int tid = threadIdx.x;
    const int nblk = blockIdx.x * 64;
    const int w = tid >> 6, lane = tid & 63;
    const int q = lane >> 4, l16 = lane & 15;

    // ---- stage x (octs 0..2), h (octs 11..18), zero-pad (oct 19): 64 nodes x 12 slots ----
#pragma unroll
    for (int i = 0; i < 3; ++i) {
        int slot = tid + 256 * i;
        int n = slot / 12, oo = slot - n * 12;
        int n_g = nblk + n;
        uint4 z = make_uint4(0, 0, 0, 0);
        if (n_g < NN) {
            if (oo < 3) {
                if (xT) {
                    z = *(const uint4*)(xT + ((size_t)t * NN + n_g) * XSTR + oo * 8);
                } else {
                    const float* xp = x + (size_t)n_g * 240 + 80 + (size_t)oo * 64 + t;
                    uint_ r[4];
#pragma unroll
                    for (int p = 0; p < 4; p++) {
                        int k0 = oo * 8 + p * 2;
                        ushort_ b0 = (k0 < 20) ? f2b(xp[p * 16]) : (ushort_)0;
                        ushort_ b1 = (k0 + 1 < 20) ? f2b(xp[p * 16 + 8]) : (ushort_)0;
                        r[p] = (uint_)b0 | ((uint_)b1 << 16);
                    }
                    z = make_uint4(r[0], r[1], r[2], r[3]);
                }
            } else if (oo < 11) {
                z = *(const uint4*)(hbR + (size_t)n_g * 64 + (oo - 3) * 8);
            }
        }
        int oct = (oo < 3) ? oo : ((oo < 11) ? (oo + 8) : 19);
        *(uint4*)(Zs + n * 168 + oct * 8) = z;
    }

    // ---- gather phase: 8-lane group per node, lane l8 owns features l8*8..+7, fp32 accum ----
    {
        int slot = tid >> 3;       // 0..31
        int l8 = tid & 7;
        for (int nn = slot; nn < 64; nn += 32) {
            int node = nblk + nn;
            float a[8];
#pragma unroll
            for (int i = 0; i < 8; i++) a[i] = 0.f;
            if (t > 0 && node < NN) {
                int e0 = off[node], e1 = off[node + 1];
                int e = e0;
                for (; e + 8 <= e1; e += 8) {
                    uint4 v0 = *(const uint4*)(hbR + (size_t)csr[e] * 64 + l8 * 8);
                    uint4 v1 = *(const uint4*)(hbR + (size_t)csr[e + 1] * 64 + l8 * 8);
                    uint4 v2 = *(const uint4*)(hbR + (size_t)csr[e + 2] * 64 + l8 * 8);
                    uint4 v3 = *(const uint4*)(hbR + (size_t)csr[e + 3] * 64 + l8 * 8);
                    uint4 v4 = *(const uint4*)(hbR + (size_t)csr[e + 4] * 64 + l8 * 8);
                    uint4 v5 = *(const uint4*)(hbR + (size_t)csr[e + 5] * 64 + l8 * 8);
                    uint4 v6 = *(const uint4*)(hbR + (size_t)csr[e + 6] * 64 + l8 * 8);
                    uint4 v7 = *(const uint4*)(hbR + (size_t)csr[e + 7] * 64 + l8 * 8);
                    acc8(a, v0); acc8(a, v1); acc8(a, v2); acc8(a, v3);
                    acc8(a, v4); acc8(a, v5); acc8(a, v6); acc8(a, v7);
                }
                for (; e < e1; e++) {
                    uint4 v0 = *(const uint4*)(hbR + (size_t)csr[e] * 64 + l8 * 8);
                    acc8(a, v0);
                }
            }
            uint4 o;
            o.x = pk(a[0], a[1]); o.y = pk(a[2], a[3]);
            o.z = pk(a[4], a[5]); o.w = pk(a[6], a[7]);
            *(uint4*)(Zs + nn * 168 + 24 + l8 * 8) = o;   // kk 24..87
        }
    }
    __syncthreads();   // Zs complete

    f32x4 acc[4][NT];
#pragma unroll
    for (int mt = 0; mt < 4; mt++)
#pragma unroll
        for (int nt = 0; nt < NT; nt++) acc[mt][nt] = (f32x4)(0.f);

#pragma unroll
    for (int kt = 0; kt < 5; ++kt) {
        bf16x8 af[4], bf[NT];
#pragma unroll
        for (int mt = 0; mt < 4; mt++)
            af[mt] = *(const bf16x8*)(Zs + (mt * 16 + l16) * 168 + kt * 32 + q * 8);
#pragma unroll
        for (int nt = 0; nt < NT; nt++) {
            int n = (nt < 4) ? (w * 64 + nt * 16 + l16) : (256 + w * 16 + l16);
            bf[nt] = *(const bf16x8*)(WgB + (size_t)n * KF + kt * 32 + q * 8);
        }
#pragma unroll
        for (int mt = 0; mt < 4; mt++)
#pragma unroll
            for (int nt = 0; nt < NT; nt++)
                acc[mt][nt] = __builtin_amdgcn_mfma_f32_16x16x32_bf16(af[mt], bf[nt], acc[mt][nt], 0, 0, 0);
    }

    // ---- epilogue: compute cell update; stage in LDS; full-line cooperative stores ----
    const int j = w * 16 + l16;
    const f32x4 bias = *(const f32x4*)(bgp + j * 4);
    const float brl = LAST ? bgp[256 + j] : 0.f;
    float sh = 0.f, sh2 = 0.f, sg = 0.f, sg2 = 0.f;

    __syncthreads();   // all Zs fragment reads done — Zs reusable
    ushort_* Hs   = Zs;                      // [64][64] bf16, bytes [0, 8192)
    float*   CsLo = (float*)(Zs + 4096);     // [32][64] fp32, bytes [8192, 16384)

    float cnHi[8];
#pragma unroll
    for (int mt = 0; mt < 4; ++mt) {
#pragma unroll
        for (int r = 0; r < 4; ++r) {
            int nloc = mt * 16 + q * 4 + r;
            int node = nblk + nloc;
            float cn = 0.f, hn = 0.f;
            if (node < NN) {
                size_t idx = (size_t)node * 64 + j;
                float iv = sigf(acc[mt][0][r] + bias.x);
                float fv = sigf(acc[mt][1][r] + bias.y);
                float gv = tanhf_(acc[mt][2][r] + bias.z);
                float ov = sigf(acc[mt][3][r] + bias.w);
                cn = fv * c[idx] + iv * gv;
                hn = ov * tanhf_(cn);
                if (LAST) {
                    float gn = acc[mt][4][r] + brl;
                    hf[idx] = hn;
                    gnn[idx] = gn;
                    sh += hn; sh2 += hn * hn;
                    sg += gn; sg2 += gn * gn;
                }
            }
            Hs[nloc * 64 + j] = f2b(hn);
            if (mt < 2) CsLo[nloc * 64 + j] = cn;
            else        cnHi[(mt - 2) * 4 + r] = cn;
        }
    }
    __syncthreads();
    // hbW: 64 rows x 128 B; c low: 32 rows x 256 B — both fully coalesced 16 B/lane
#pragma unroll
    for (int i = 0; i < 2; ++i) {
        int s = tid + 256 * i;
        {
            int n = s >> 3, part = s & 7;
            if (nblk + n < NN)
                *(uint4*)(hbW + (size_t)(nblk + n) * 64 + part * 8) =
                    *(const uint4*)(Hs + n * 64 + part * 8);
        }
        {
            int n = s >> 4, part = s & 15;
            if (nblk + n < NN)
                *(float4*)(c + (size_t)(nblk + n) * 64 + part * 4) =
                    *(const float4*)(CsLo + n * 64 + part * 4);
        }
    }
    __syncthreads();
    float* CsHi = (float*)Zs;   // [32][64] for nodes 32..63
#pragma unroll
    for (int mt = 2; mt < 4; ++mt)
#pragma unroll
        for (int r = 0; r < 4; ++r) {
            int nloc = mt * 16 + q * 4 + r;
            CsHi[(nloc - 32) * 64 + j] = cnHi[(mt - 2) * 4 + r];
        }
    __syncthreads();
#pragma unroll
    for (int i = 0; i < 2; ++i) {
        int s = tid + 256 * i;
        int n = 32 + (s >> 4), part = s & 15;
        if (nblk + n < NN)
            *(float4*)(c + (size_t)(nblk + n) * 64 + part * 4) =
                *(const float4*)(CsHi + (n - 32) * 64 + part * 4);
    }

    if (LAST) {
#pragma unroll
        for (int d = 16; d < 64; d <<= 1) {
            sh += __shfl_xor(sh, d, 64);
            sh2 += __shfl_xor(sh2, d, 64);
            sg += __shfl_xor(sg, d, 64);
            sg2 += __shfl_xor(sg2, d, 64);
        }
        if (q == 0) {
            atomicAdd(&sums[j], sh);
            atomicAdd(&sumsq[j], sh2);
            atomicAdd(&sums[64 + j], sg);
            atomicAdd(&sumsq[64 + j], sg2);
        }
    }
}

__global__ __launch_bounds__(256, 4) void k_step(const float* __restrict__ x,
                                                 const ushort_* __restrict__ xT,
                                                 const int* __restrict__ off,
                                                 const int* __restrict__ csr,
                                                 const ushort_* __restrict__ hbR,
                                                 ushort_* __restrict__ hbW,
                                                 float* __restrict__ hf,
                                                 float* __restrict__ c,
                                                 const ushort_* __restrict__ WgB,
                                                 const float* __restrict__ bgp, int t) {
    step_body<false>(x, xT, off, csr, hbR, hbW, hf, c, WgB, bgp, nullptr, nullptr, nullptr, t);
}

__global__ __launch_bounds__(256, 4) void k_stepL(const float* __restrict__ x,
                                                  const ushort_* __restrict__ xT,
                                                  const int* __restrict__ off,
                                                  const int* __restrict__ csr,
                                                  const ushort_* __restrict__ hbR,
                                                  ushort_* __restrict__ hbW,
                                                  float* __restrict__ hf,
                                                  float* __restrict__ c,
                                                  const ushort_* __restrict__ WgB,
                                                  const float* __restrict__ bgp,
                                                  float* __restrict__ gnn,
                                                  float* __restrict__ sums,
                                                  float* __restrict__ sumsq, int t) {
    step_body<true>(x, xT, off, csr, hbR, hbW, hf, c, WgB, bgp, gnn, sums, sumsq, t);
}

// ---------------- MFMA head: BN-apply + relu(W1) + relu(W2) + sigmoid(W_out) ----------------
__global__ __launch_bounds__(256) void k_head(const float* __restrict__ hf,
                                              const float* __restrict__ gnn,
                                              const float* __restrict__ sums,
                                              const float* __restrict__ sumsq,
                                              const float* __restrict__ gamma,
                                              const float* __restrict__ beta,
                                              const float* __restrict__ W1,
                                              const float* __restrict__ b1,
                                              const float* __restrict__ W2,
                                              const float* __restrict__ b2,
                                              const float* __restrict__ W_out,
                                              const float* __restrict__ b_out,
                                              float* __restrict__ out) {
    __shared__ __align__(16) ushort_ Zs[64 * 168];    // normed [node][F pad]
    __shared__ __align__(16) ushort_ W1s[64 * 168];   // W1 rows [j][k=128 pad]
    __shared__ __align__(16) ushort_ W2s[128 * 72];   // W2 rows [j2][k=64 pad]
    __shared__ __align__(16) ushort_ H1s[64 * 72];    // h1 bf16 [node][j pad]
    __shared__ float ab[256];
    __shared__ float Obuf[4][64];
    const int tid = threadIdx.x;
    const int w = tid >> 6, lane = tid & 63;
    const int q = lane >> 4, l16 = lane & 15;

    if (tid < 128) {
        float mean = sums[tid] / (float)NN;
        float var = sumsq[tid] / (float)NN - mean * mean;
        float a = gamma[tid] * rsqrtf(var + 1e-5f);
        ab[tid] = a;
        ab[128 + tid] = beta[tid] - mean * a;
    }
#pragma unroll
    for (int i = 0; i < 8; ++i) {
        int slot = tid + 256 * i;
        int jj = slot >> 5, k4 = slot & 31;
        float4 v = *(const float4*)(W1 + (size_t)jj * 128 + k4 * 4);
        *(uint2*)(W1s + jj * 168 + k4 * 4) = make_uint2(pk(v.x, v.y), pk(v.z, v.w));
    }
#pragma unroll
    for (int i = 0; i < 8; ++i) {
        int slot = tid + 256 * i;
        int jj = slot >> 4, k4 = slot & 15;
        float4 v = *(const float4*)(W2 + (size_t)jj * 64 + k4 * 4);
        *(uint2*)(W2s + jj * 72 + k4 * 4) = make_uint2(pk(v.x, v.y), pk(v.z, v.w));
    }
    const int j1 = w * 16 + l16;
    const float bb1 = b1[j1];
    const int j2a = (w * 2) * 16 + l16, j2b = (w * 2 + 1) * 16 + l16;
    const float bb2a = b2[j2a], bb2b = b2[j2b];
    const float woa = W_out[j2a], wob = W_out[j2b];
    const float bo = b_out[0];
    __syncthreads();

    const int NTILE = (NN + 63) / 64;
    for (int tile = blockIdx.x; tile < NTILE; tile += gridDim.x) {
        const int nblk = tile * 64;
#pragma unroll
        for (int i = 0; i < 8; ++i) {
            int slot = tid + 256 * i;
            int n = slot >> 5, f4 = slot & 31;
            int n_g = nblk + n;
            uint2 z = make_uint2(0, 0);
            if (n_g < NN) {
                const float* src = (f4 < 16) ? (hf + (size_t)n_g * 64 + f4 * 4)
                                             : (gnn + (size_t)n_g * 64 + (f4 - 16) * 4);
                float4 v = *(const float4*)src;
                int F = f4 * 4;
                z = make_uint2(pk(v.x * ab[F] + ab[128 + F], v.y * ab[F + 1] + ab[129 + F]),
                               pk(v.z * ab[F + 2] + ab[130 + F], v.w * ab[F + 3] + ab[131 + F]));
            }
            *(uint2*)(Zs + n * 168 + f4 * 4) = z;
        }
        __syncthreads();
        f32x4 acc1[4];
#pragma unroll
        for (int mt = 0; mt < 4; mt++) acc1[mt] = (f32x4)(0.f);
#pragma unroll
        for (int kt = 0; kt < 4; ++kt) {
            bf16x8 bfw = *(const bf16x8*)(W1s + j1 * 168 + kt * 32 + q * 8);
#pragma unroll
            for (int mt = 0; mt < 4; mt++) {
                bf16x8 af = *(const bf16x8*)(Zs + (mt * 16 + l16) * 168 + kt * 32 + q * 8);
                acc1[mt] = __builtin_amdgcn_mfma_f32_16x16x32_bf16(af, bfw, acc1[mt], 0, 0, 0);
            }
        }
#pragma unroll
        for (int mt = 0; mt < 4; mt++)
#pragma unroll
            for (int r = 0; r < 4; r++) {
                int nloc = mt * 16 + q * 4 + r;
                H1s[nloc * 72 + j1] = f2b(fmaxf(acc1[mt][r] + bb1, 0.f));
            }
        __syncthreads();
        f32x4 acc2[4][2];
#pragma unroll
        for (int mt = 0; mt < 4; mt++)
#pragma unroll
            for (int nt = 0; nt < 2; nt++) acc2[mt][nt] = (f32x4)(0.f);
#pragma unroll
        for (int kt = 0; kt < 2; ++kt) {
            bf16x8 bfa = *(const bf16x8*)(W2s + j2a * 72 + kt * 32 + q * 8);
            bf16x8 bfb = *(const bf16x8*)(W2s + j2b * 72 + kt * 32 + q * 8);
#pragma unroll
            for (int mt = 0; mt < 4; mt++) {
                bf16x8 af = *(const bf16x8*)(H1s + (mt * 16 + l16) * 72 + kt * 32 + q * 8);
                acc2[mt][0] = __builtin_amdgcn_mfma_f32_16x16x32_bf16(af, bfa, acc2[mt][0], 0, 0, 0);
                acc2[mt][1] = __builtin_amdgcn_mfma_f32_16x16x32_bf16(af, bfb, acc2[mt][1], 0, 0, 0);
            }
        }
#pragma unroll
        for (int mt = 0; mt < 4; mt++) {
#pragma unroll
            for (int r = 0; r < 4; r++) {
                float p = fmaxf(acc2[mt][0][r] + bb2a, 0.f) * woa +
                          fmaxf(acc2[mt][1][r] + bb2b, 0.f) * wob;
#pragma unroll
                for (int d = 1; d < 16; d <<= 1) p += __shfl_xor(p, d, 64);
                if (l16 == 0) Obuf[w][mt * 16 + q * 4 + r] = p;
            }
        }
        __syncthreads();
        if (tid < 64) {
            int n_g = nblk + tid;
            if (n_g < NN) {
                float s = Obuf[0][tid] + Obuf[1][tid] + Obuf[2][tid] + Obuf[3][tid];
                out[n_g] = sigf(s + bo);
            }
        }
        __syncthreads();
    }
}

extern "C" void kernel_launch(void* const* d_in, const int* in_sizes, int n_in,
                              void* d_out, int out_size, void* d_ws, size_t ws_size,
                              hipStream_t stream) {
    const float* x      = (const float*)d_in[0];
    const int*   ei     = (const int*)d_in[1];
    const float* W_ih   = (const float*)d_in[4];
    const float* W_hh   = (const float*)d_in[5];
    const float* b_ih   = (const float*)d_in[6];
    const float* b_hh   = (const float*)d_in[7];
    const float* W_rel  = (const float*)d_in[8];
    const float* b_rel  = (const float*)d_in[9];
    const float* W_root = (const float*)d_in[10];
    const float* gamma  = (const float*)d_in[11];
    const float* beta   = (const float*)d_in[12];
    const float* W1     = (const float*)d_in[13];
    const float* b1     = (const float*)d_in[14];
    const float* W2     = (const float*)d_in[15];
    const float* b2     = (const float*)d_in[16];
    const float* W_out  = (const float*)d_in[17];
    const float* b_out  = (const float*)d_in[18];
    float* out = (float*)d_out;

    char* ws = (char*)d_ws;
    size_t o = 0;
    auto carve = [&](size_t bytes) { char* p = ws + o; o += (bytes + 255) & ~(size_t)255; return p; };
    int*     off   = (int*)carve((NN + 1) * 4);
    int*     cnt   = (int*)carve(NN * 4);          // reused as cursor
    int*     bsum  = (int*)carve(128 * 4);
    int*     flag  = (int*)carve(256);
    int*     csr   = (int*)carve((size_t)NE * 4);
    float*   hf    = (float*)carve((size_t)NN * 64 * 4);   // fp32 h (written at t=7 only)
    float*   c     = (float*)carve((size_t)NN * 64 * 4);
    float*   gnn   = (float*)carve((size_t)NN * 64 * 4);
    ushort_* hbA   = (ushort_*)carve((size_t)NN * 64 * 2); // bf16 h ping
    ushort_* hbB   = (ushort_*)carve((size_t)NN * 64 * 2); // bf16 h pong
    ushort_* WgB   = (ushort_*)carve((size_t)320 * KF * 2);
    float*   bgp   = (float*)carve(320 * 4);
    float*   sums  = (float*)carve(128 * 4);
    float*   sumsq = (float*)carve(128 * 4);
    ushort_* xT = nullptr;
    size_t need_xt = (size_t)TT * NN * XSTR * 2;
    if (o + need_xt + 256 <= ws_size) xT = (ushort_*)carve(need_xt);

    const int nscan = (NN + 1023) / 1024;   // 98
    const int xtb = xT ? (NN * XSTR + 255) / 256 : 0;

    // edge dtype detect + CSR build (+ x transpose overlapped with hist)
    hipMemsetAsync(flag, 0, 4, stream);
    hipMemsetAsync(cnt, 0, NN * 4, stream);
    k_detect<<<16, 256, 0, stream>>>(ei, flag);
    k_hist_xt<<<HISTB + xtb, 256, 0, stream>>>(ei, flag, cnt, x, xT);
    k_scanblk<<<nscan, 1024, 0, stream>>>(cnt, off, bsum);
    k_scantop<<<1, 64, 0, stream>>>(bsum, nscan);
    k_scanadd<<<nscan, 1024, 0, stream>>>(off, bsum);
    hipMemcpyAsync(cnt, off, NN * 4, hipMemcpyDeviceToDevice, stream);  // cursor = off
    k_scatter<<<(NE / 256) * NRANGE, 256, 0, stream>>>(ei, flag, cnt, csr);

    // init state + folded weights + BN accumulators
    hipMemsetAsync(c, 0, (size_t)NN * 64 * 4, stream);
    hipMemsetAsync(hbA, 0, (size_t)NN * 64 * 2, stream);   // t=0 reads hbA
    hipMemsetAsync(sums, 0, 1024, stream);                 // sums + sumsq (contiguous carves)
    k_prep<<<KF + 1, 320, 0, stream>>>(W_ih, W_hh, b_ih, b_hh, W_rel, b_rel, W_root, WgB, bgp);

    // 8 fused steps (ping-pong bf16 h)
    const int ngates = (NN + 63) / 64;
    for (int t = 0; t < TT; ++t) {
        ushort_* hbR = (t & 1) ? hbB : hbA;
        ushort_* hbW = (t & 1) ? hbA : hbB;
        if (t == TT - 1)
            k_stepL<<<ngates, 256, 0, stream>>>(x, xT, off, csr, hbR, hbW, hf, c,
                                                WgB, bgp, gnn, sums, sumsq, t);
        else
            k_step<<<ngates, 256, 0, stream>>>(x, xT, off, csr, hbR, hbW, hf, c,
                                               WgB, bgp, t);
    }

    // fused MFMA head
    k_head<<<512, 256, 0, stream>>>(hf, gnn, sums, sumsq, gamma, beta,
                                    W1, b1, W2, b2, W_out, b_out, out);
}